// Round 1
// baseline (191.836 us; speedup 1.0000x reference)
//
#include <hip/hip_runtime.h>

#define JOINTS 24

// SMPL 24-joint tree; parents[j] < j, root parent = -1.
__device__ __constant__ // (not used: kept compile-time below)
static const int dummy_unused = 0;

__global__ __launch_bounds__(256) void fk_kernel(
    const float* __restrict__ rot,      // [B, 24, 4]
    const float* __restrict__ skel,     // [24, 3]
    float* __restrict__ out,            // [B, 24, 3]
    int B)
{
    const int b = blockIdx.x * blockDim.x + threadIdx.x;
    if (b >= B) return;

    constexpr int parents[JOINTS] = {-1, 0, 0, 0, 1, 2, 3, 4, 5, 6, 7, 8,
                                      9, 9, 9, 12, 13, 14, 16, 17, 18, 19, 20, 21};

    // Quats for this batch: 24 x float4, 16B aligned (b*384 bytes offset).
    const float4* __restrict__ q4 =
        reinterpret_cast<const float4*>(rot + (size_t)b * (JOINTS * 4));

    float pos[JOINTS][3];
    pos[0][0] = 0.0f; pos[0][1] = 0.0f; pos[0][2] = 0.0f;

#pragma unroll
    for (int j = 1; j < JOINTS; ++j) {
        const int p = parents[j];
        // bone offset in rest pose (lane-uniform scalar loads, cached)
        const float ox = skel[j * 3 + 0] - skel[p * 3 + 0];
        const float oy = skel[j * 3 + 1] - skel[p * 3 + 1];
        const float oz = skel[j * 3 + 2] - skel[p * 3 + 2];

        const float4 qj = q4[j];
        const float w = qj.x, x = qj.y, y = qj.z, z = qj.w;

        // R(q) @ offset (no quat normalization, faithful to reference)
        const float r00 = 1.0f - 2.0f * (y * y + z * z);
        const float r01 = 2.0f * (x * y - z * w);
        const float r02 = 2.0f * (x * z + y * w);
        const float r10 = 2.0f * (x * y + z * w);
        const float r11 = 1.0f - 2.0f * (x * x + z * z);
        const float r12 = 2.0f * (y * z - x * w);
        const float r20 = 2.0f * (x * z - y * w);
        const float r21 = 2.0f * (y * z + x * w);
        const float r22 = 1.0f - 2.0f * (x * x + y * y);

        const float rx = r00 * ox + r01 * oy + r02 * oz;
        const float ry = r10 * ox + r11 * oy + r12 * oz;
        const float rz = r20 * ox + r21 * oy + r22 * oz;

        pos[j][0] = pos[p][0] + rx;
        pos[j][1] = pos[p][1] + ry;
        pos[j][2] = pos[p][2] + rz;
    }

    // Store 72 contiguous floats as 18 x float4 (b*288 bytes offset, 16B aligned).
    float4* __restrict__ o4 =
        reinterpret_cast<float4*>(out + (size_t)b * (JOINTS * 3));
    const float* pf = &pos[0][0];
#pragma unroll
    for (int i = 0; i < 18; ++i) {
        o4[i] = make_float4(pf[i * 4 + 0], pf[i * 4 + 1],
                            pf[i * 4 + 2], pf[i * 4 + 3]);
    }
}

extern "C" void kernel_launch(void* const* d_in, const int* in_sizes, int n_in,
                              void* d_out, int out_size, void* d_ws, size_t ws_size,
                              hipStream_t stream) {
    const float* rot  = (const float*)d_in[0];   // [B, 24, 4] f32
    const float* skel = (const float*)d_in[1];   // [24, 3] f32
    float* out = (float*)d_out;                  // [B, 24, 3] f32

    const int B = in_sizes[0] / (JOINTS * 4);    // 524288
    const int block = 256;
    const int grid = (B + block - 1) / block;    // 2048
    fk_kernel<<<grid, block, 0, stream>>>(rot, skel, out, B);
}

// Round 2
// 111.822 us; speedup vs baseline: 1.7155x; 1.7155x over previous
//
#include <hip/hip_runtime.h>

#define JOINTS 24
#define BLOCK 256
#define HALF 128
#define LDS_STRIDE 73   // 72 floats payload + 1 pad (73%32=9, coprime with 32 -> conflict-free writes)

__global__ __launch_bounds__(256) void fk_kernel(
    const float* __restrict__ rot,      // [B, 24, 4]
    const float* __restrict__ skel,     // [24, 3]
    float* __restrict__ out,            // [B, 24, 3]
    int B)
{
    __shared__ float sbuf[HALF * LDS_STRIDE];   // 37376 B

    const int tid = threadIdx.x;
    const int b   = blockIdx.x * BLOCK + tid;

    constexpr int parents[JOINTS] = {-1, 0, 0, 0, 1, 2, 3, 4, 5, 6, 7, 8,
                                      9, 9, 9, 12, 13, 14, 16, 17, 18, 19, 20, 21};

    float pos[JOINTS][3];
    pos[0][0] = 0.0f; pos[0][1] = 0.0f; pos[0][2] = 0.0f;

    if (b < B) {
        const float4* __restrict__ q4 =
            reinterpret_cast<const float4*>(rot + (size_t)b * (JOINTS * 4));
#pragma unroll
        for (int j = 1; j < JOINTS; ++j) {
            const int p = parents[j];
            const float ox = skel[j * 3 + 0] - skel[p * 3 + 0];
            const float oy = skel[j * 3 + 1] - skel[p * 3 + 1];
            const float oz = skel[j * 3 + 2] - skel[p * 3 + 2];

            const float4 qj = q4[j];
            const float w = qj.x, x = qj.y, y = qj.z, z = qj.w;

            const float r00 = 1.0f - 2.0f * (y * y + z * z);
            const float r01 = 2.0f * (x * y - z * w);
            const float r02 = 2.0f * (x * z + y * w);
            const float r10 = 2.0f * (x * y + z * w);
            const float r11 = 1.0f - 2.0f * (x * x + z * z);
            const float r12 = 2.0f * (y * z - x * w);
            const float r20 = 2.0f * (x * z - y * w);
            const float r21 = 2.0f * (y * z + x * w);
            const float r22 = 1.0f - 2.0f * (x * x + y * y);

            pos[j][0] = pos[p][0] + r00 * ox + r01 * oy + r02 * oz;
            pos[j][1] = pos[p][1] + r10 * ox + r11 * oy + r12 * oz;
            pos[j][2] = pos[p][2] + r20 * ox + r21 * oy + r22 * oz;
        }
    } else {
#pragma unroll
        for (int j = 1; j < JOINTS; ++j) {
            pos[j][0] = 0.0f; pos[j][1] = 0.0f; pos[j][2] = 0.0f;
        }
    }

    // Two staging passes of 128 batches each; all 4 waves store coalesced.
    const long long blockBase = (long long)blockIdx.x * BLOCK * 72;   // floats
    const long long limit     = (long long)B * 72;

#pragma unroll
    for (int p = 0; p < 2; ++p) {
        __syncthreads();
        if ((tid >> 7) == p) {
            const int lb = tid & (HALF - 1);
            const float* pf = &pos[0][0];
#pragma unroll
            for (int f = 0; f < 72; ++f)
                sbuf[lb * LDS_STRIDE + f] = pf[f];
        }
        __syncthreads();

        const long long passBase = blockBase + (long long)p * HALF * 72;  // floats
        float4* __restrict__ o4 = reinterpret_cast<float4*>(out + passBase);
#pragma unroll
        for (int k = 0; k < 9; ++k) {
            const int F  = k * BLOCK + tid;     // float4 index within pass region
            const int g  = F * 4;               // float index within pass region
            const int lb = g / 72;              // local batch 0..127
            const int f  = g % 72;              // 0..68, multiple of 4
            if (passBase + g < limit) {
                float4 v;
                v.x = sbuf[lb * LDS_STRIDE + f + 0];
                v.y = sbuf[lb * LDS_STRIDE + f + 1];
                v.z = sbuf[lb * LDS_STRIDE + f + 2];
                v.w = sbuf[lb * LDS_STRIDE + f + 3];
                o4[F] = v;
            }
        }
    }
}

extern "C" void kernel_launch(void* const* d_in, const int* in_sizes, int n_in,
                              void* d_out, int out_size, void* d_ws, size_t ws_size,
                              hipStream_t stream) {
    const float* rot  = (const float*)d_in[0];   // [B, 24, 4] f32
    const float* skel = (const float*)d_in[1];   // [24, 3] f32
    float* out = (float*)d_out;                  // [B, 24, 3] f32

    const int B = in_sizes[0] / (JOINTS * 4);    // 524288
    const int grid = (B + BLOCK - 1) / BLOCK;    // 2048
    fk_kernel<<<grid, BLOCK, 0, stream>>>(rot, skel, out, B);
}

// Round 3
// 85.290 us; speedup vs baseline: 2.2492x; 1.3111x over previous
//
#include <hip/hip_runtime.h>

#define JOINTS 24

// Involution swizzle on 16B units: XOR low 4 bits with bits 4-7.
// Makes stride-8 (128B) transposed LDS reads bank-conflict-free while the
// linear (coalesced) side stays a within-16-block permutation.
__device__ __forceinline__ int swz(int u) { return u ^ ((u >> 4) & 15); }

__device__ constexpr int kParents[JOINTS] = {-1, 0, 0, 0, 1, 2, 3, 4, 5, 6, 7, 8,
                                             9, 9, 9, 12, 13, 14, 16, 17, 18, 19, 20, 21};

template <int J>
__device__ __forceinline__ void do_joint(float (*pos)[3], const float4 qj,
                                         const float* __restrict__ skel) {
    constexpr int P = kParents[J];
    const float ox = skel[J * 3 + 0] - skel[P * 3 + 0];
    const float oy = skel[J * 3 + 1] - skel[P * 3 + 1];
    const float oz = skel[J * 3 + 2] - skel[P * 3 + 2];
    const float w = qj.x, x = qj.y, y = qj.z, z = qj.w;
    const float r00 = 1.f - 2.f * (y * y + z * z);
    const float r01 = 2.f * (x * y - z * w);
    const float r02 = 2.f * (x * z + y * w);
    const float r10 = 2.f * (x * y + z * w);
    const float r11 = 1.f - 2.f * (x * x + z * z);
    const float r12 = 2.f * (y * z - x * w);
    const float r20 = 2.f * (x * z - y * w);
    const float r21 = 2.f * (y * z + x * w);
    const float r22 = 1.f - 2.f * (x * x + y * y);
    pos[J][0] = pos[P][0] + r00 * ox + r01 * oy + r02 * oz;
    pos[J][1] = pos[P][1] + r10 * ox + r11 * oy + r12 * oz;
    pos[J][2] = pos[P][2] + r20 * ox + r21 * oy + r22 * oz;
}

template <int C>  // joints 8C .. 8C+7, quats q[0..7]
__device__ __forceinline__ void compute_chunk(float (*pos)[3], const float4* q,
                                              const float* __restrict__ skel) {
    if constexpr (C == 0) {
        pos[0][0] = 0.f; pos[0][1] = 0.f; pos[0][2] = 0.f;
        do_joint<1>(pos, q[1], skel); do_joint<2>(pos, q[2], skel);
        do_joint<3>(pos, q[3], skel); do_joint<4>(pos, q[4], skel);
        do_joint<5>(pos, q[5], skel); do_joint<6>(pos, q[6], skel);
        do_joint<7>(pos, q[7], skel);
    } else if constexpr (C == 1) {
        do_joint<8>(pos, q[0], skel);  do_joint<9>(pos, q[1], skel);
        do_joint<10>(pos, q[2], skel); do_joint<11>(pos, q[3], skel);
        do_joint<12>(pos, q[4], skel); do_joint<13>(pos, q[5], skel);
        do_joint<14>(pos, q[6], skel); do_joint<15>(pos, q[7], skel);
    } else {
        do_joint<16>(pos, q[0], skel); do_joint<17>(pos, q[1], skel);
        do_joint<18>(pos, q[2], skel); do_joint<19>(pos, q[3], skel);
        do_joint<20>(pos, q[4], skel); do_joint<21>(pos, q[5], skel);
        do_joint<22>(pos, q[6], skel); do_joint<23>(pos, q[7], skel);
    }
}

// Stage 64 batches x 8 quats (chunk c) into this wave's LDS slice via
// global_load_lds, then read each lane's 8 quats (transposed, conflict-free).
__device__ __forceinline__ void load_chunk(const float4* __restrict__ rot4,
                                           float4* slice, int wb, int lane, int c,
                                           float4* q) {
    // prior ds_reads of this slice must be retired before glds overwrites it
    asm volatile("s_waitcnt lgkmcnt(0)" ::: "memory");
    __builtin_amdgcn_sched_barrier(0);
#pragma unroll
    for (int k = 0; k < 8; ++k) {
        const int u = k * 64 + lane;       // physical 16B unit this lane fills
        const int L = swz(u);              // logical element stored there
        const int row = L >> 3, col = L & 7;
        const float4* src = rot4 + ((size_t)(wb + row) * 24 + c * 8 + col);
        __builtin_amdgcn_global_load_lds(
            (const __attribute__((address_space(1))) void*)src,
            (__attribute__((address_space(3))) void*)(slice + k * 64),
            16, 0, 0);
    }
    asm volatile("s_waitcnt vmcnt(0)" ::: "memory");
    __builtin_amdgcn_sched_barrier(0);
#pragma unroll
    for (int j = 0; j < 8; ++j)
        q[j] = slice[swz(lane * 8 + j)];   // lane's own batch, quats 8c..8c+7
}

template <int OC>  // joints 8*OC .. 8*OC+7 -> 24 floats = 6 float4 per batch
__device__ __forceinline__ void store_chunk(float (*pos)[3], float4* slice,
                                            float4* __restrict__ out4, int wb, int lane) {
    asm volatile("s_waitcnt lgkmcnt(0)" ::: "memory");
    __builtin_amdgcn_sched_barrier(0);
#pragma unroll
    for (int i = 0; i < 6; ++i) {
        float v[4];
#pragma unroll
        for (int t = 0; t < 4; ++t) {
            const int f = i * 4 + t;                 // 0..23, compile-time
            v[t] = pos[OC * 8 + f / 3][f % 3];
        }
        slice[swz(lane * 8 + i)] = make_float4(v[0], v[1], v[2], v[3]);
    }
    asm volatile("s_waitcnt lgkmcnt(0)" ::: "memory");
    __builtin_amdgcn_sched_barrier(0);
#pragma unroll
    for (int k = 0; k < 8; ++k) {
        const int u = k * 64 + lane;                 // logical unit, linear
        const float4 vv = slice[swz(u)];
        const int row = u >> 3, col = u & 7;
        if (col < 6)
            out4[(size_t)(wb + row) * 18 + OC * 6 + col] = vv;
    }
}

__global__ __launch_bounds__(256) void fk_kernel(
    const float* __restrict__ rot,      // [B, 24, 4]
    const float* __restrict__ skel,     // [24, 3]
    float* __restrict__ out,            // [B, 24, 3]
    int B)
{
    __shared__ float4 lds[4 * 512];     // 32 KiB; one 8 KiB slice per wave

    const int tid  = threadIdx.x;
    const int lane = tid & 63;
    const int wv   = tid >> 6;
    const int wb   = blockIdx.x * 256 + wv * 64;   // first batch of this wave

    float4* slice = &lds[wv * 512];
    const float4* rot4 = reinterpret_cast<const float4*>(rot);
    float4* out4 = reinterpret_cast<float4*>(out);

    if (wb + 64 <= B) {
        float pos[JOINTS][3];
        float4 q[8];

        load_chunk(rot4, slice, wb, lane, 0, q);
        compute_chunk<0>(pos, q, skel);
        load_chunk(rot4, slice, wb, lane, 1, q);
        compute_chunk<1>(pos, q, skel);
        store_chunk<0>(pos, slice, out4, wb, lane);
        load_chunk(rot4, slice, wb, lane, 2, q);
        compute_chunk<2>(pos, q, skel);
        store_chunk<1>(pos, slice, out4, wb, lane);
        store_chunk<2>(pos, slice, out4, wb, lane);
    } else {
        // Partial-wave fallback (unused at B=524288): direct per-lane path.
        const int b = wb + lane;
        if (b >= B) return;
        constexpr int parents[JOINTS] = {-1, 0, 0, 0, 1, 2, 3, 4, 5, 6, 7, 8,
                                         9, 9, 9, 12, 13, 14, 16, 17, 18, 19, 20, 21};
        const float4* q4 = rot4 + (size_t)b * 24;
        float pos[JOINTS][3];
        pos[0][0] = 0.f; pos[0][1] = 0.f; pos[0][2] = 0.f;
#pragma unroll
        for (int j = 1; j < JOINTS; ++j) {
            const int p = parents[j];
            const float ox = skel[j * 3 + 0] - skel[p * 3 + 0];
            const float oy = skel[j * 3 + 1] - skel[p * 3 + 1];
            const float oz = skel[j * 3 + 2] - skel[p * 3 + 2];
            const float4 qj = q4[j];
            const float w = qj.x, x = qj.y, y = qj.z, z = qj.w;
            const float r00 = 1.f - 2.f * (y * y + z * z);
            const float r01 = 2.f * (x * y - z * w);
            const float r02 = 2.f * (x * z + y * w);
            const float r10 = 2.f * (x * y + z * w);
            const float r11 = 1.f - 2.f * (x * x + z * z);
            const float r12 = 2.f * (y * z - x * w);
            const float r20 = 2.f * (x * z - y * w);
            const float r21 = 2.f * (y * z + x * w);
            const float r22 = 1.f - 2.f * (x * x + y * y);
            pos[j][0] = pos[p][0] + r00 * ox + r01 * oy + r02 * oz;
            pos[j][1] = pos[p][1] + r10 * ox + r11 * oy + r12 * oz;
            pos[j][2] = pos[p][2] + r20 * ox + r21 * oy + r22 * oz;
        }
        float* o = out + (size_t)b * 72;
#pragma unroll
        for (int j = 0; j < JOINTS; ++j) {
            o[j * 3 + 0] = pos[j][0];
            o[j * 3 + 1] = pos[j][1];
            o[j * 3 + 2] = pos[j][2];
        }
    }
}

extern "C" void kernel_launch(void* const* d_in, const int* in_sizes, int n_in,
                              void* d_out, int out_size, void* d_ws, size_t ws_size,
                              hipStream_t stream) {
    const float* rot  = (const float*)d_in[0];   // [B, 24, 4] f32
    const float* skel = (const float*)d_in[1];   // [24, 3] f32
    float* out = (float*)d_out;                  // [B, 24, 3] f32

    const int B = in_sizes[0] / (JOINTS * 4);    // 524288
    const int grid = (B + 255) / 256;            // 2048
    fk_kernel<<<grid, 256, 0, stream>>>(rot, skel, out, B);
}

// Round 4
// 81.688 us; speedup vs baseline: 2.3484x; 1.0441x over previous
//
#include <hip/hip_runtime.h>

#define JOINTS 24

// Involution swizzle on 16B units within a 512-unit (8KiB) slice:
// XOR low 4 bits with bits 4-7. Keeps glds destinations linear while making
// stride-8 transposed ds_reads (mostly) bank-conflict-free.
__device__ __forceinline__ int swz(int u) { return u ^ ((u >> 4) & 15); }

__device__ constexpr int kParents[JOINTS] = {-1, 0, 0, 0, 1, 2, 3, 4, 5, 6, 7, 8,
                                             9, 9, 9, 12, 13, 14, 16, 17, 18, 19, 20, 21};

template <int J>
__device__ __forceinline__ void do_joint(float (*pos)[3], const float4 qj,
                                         const float* __restrict__ skel) {
    constexpr int P = kParents[J];
    const float ox = skel[J * 3 + 0] - skel[P * 3 + 0];
    const float oy = skel[J * 3 + 1] - skel[P * 3 + 1];
    const float oz = skel[J * 3 + 2] - skel[P * 3 + 2];
    const float w = qj.x, x = qj.y, y = qj.z, z = qj.w;
    const float r00 = 1.f - 2.f * (y * y + z * z);
    const float r01 = 2.f * (x * y - z * w);
    const float r02 = 2.f * (x * z + y * w);
    const float r10 = 2.f * (x * y + z * w);
    const float r11 = 1.f - 2.f * (x * x + z * z);
    const float r12 = 2.f * (y * z - x * w);
    const float r20 = 2.f * (x * z - y * w);
    const float r21 = 2.f * (y * z + x * w);
    const float r22 = 1.f - 2.f * (x * x + y * y);
    pos[J][0] = pos[P][0] + r00 * ox + r01 * oy + r02 * oz;
    pos[J][1] = pos[P][1] + r10 * ox + r11 * oy + r12 * oz;
    pos[J][2] = pos[P][2] + r20 * ox + r21 * oy + r22 * oz;
}

template <int C>  // joints 8C .. 8C+7 from q[0..7]
__device__ __forceinline__ void compute_chunk(float (*pos)[3], const float4* q,
                                              const float* __restrict__ skel) {
    if constexpr (C == 0) {
        pos[0][0] = 0.f; pos[0][1] = 0.f; pos[0][2] = 0.f;
        do_joint<1>(pos, q[1], skel); do_joint<2>(pos, q[2], skel);
        do_joint<3>(pos, q[3], skel); do_joint<4>(pos, q[4], skel);
        do_joint<5>(pos, q[5], skel); do_joint<6>(pos, q[6], skel);
        do_joint<7>(pos, q[7], skel);
    } else if constexpr (C == 1) {
        do_joint<8>(pos, q[0], skel);  do_joint<9>(pos, q[1], skel);
        do_joint<10>(pos, q[2], skel); do_joint<11>(pos, q[3], skel);
        do_joint<12>(pos, q[4], skel); do_joint<13>(pos, q[5], skel);
        do_joint<14>(pos, q[6], skel); do_joint<15>(pos, q[7], skel);
    } else {
        do_joint<16>(pos, q[0], skel); do_joint<17>(pos, q[1], skel);
        do_joint<18>(pos, q[2], skel); do_joint<19>(pos, q[3], skel);
        do_joint<20>(pos, q[4], skel); do_joint<21>(pos, q[5], skel);
        do_joint<22>(pos, q[6], skel); do_joint<23>(pos, q[7], skel);
    }
}

// Issue 8 global_load_lds (width 16) staging 64 batches x 8 quats of chunk c
// into this wave's slice. Fire-and-forget: caller manages vmcnt.
__device__ __forceinline__ void issue_glds(const float4* __restrict__ rot4,
                                           float4* slice, int wb, int lane, int c) {
#pragma unroll
    for (int k = 0; k < 8; ++k) {
        const int u = k * 64 + lane;       // physical 16B unit this lane fills
        const int L = swz(u);              // logical element stored there
        const int row = L >> 3, col = L & 7;
        const float4* src = rot4 + ((size_t)(wb + row) * 24 + c * 8 + col);
        __builtin_amdgcn_global_load_lds(
            (const __attribute__((address_space(1))) void*)src,
            (__attribute__((address_space(3))) void*)(slice + k * 64),
            16, 0, 0);
    }
}

// Transposed read of this lane's 8 quats; drains lgkm so the slice may be
// safely overwritten right after.
__device__ __forceinline__ void read_q(const float4* slice, int lane, float4* q) {
#pragma unroll
    for (int j = 0; j < 8; ++j)
        q[j] = slice[swz(lane * 8 + j)];
    asm volatile("s_waitcnt lgkmcnt(0)" ::: "memory");
    __builtin_amdgcn_sched_barrier(0);
}

template <int OC>  // joints 8*OC .. 8*OC+7 -> 6 float4 per batch, coalesced out
__device__ __forceinline__ void store_chunk(const float (*pos)[3], float4* slice,
                                            float4* __restrict__ out4, int wb, int lane) {
    asm volatile("s_waitcnt lgkmcnt(0)" ::: "memory");   // slice's prior ds ops done
    __builtin_amdgcn_sched_barrier(0);
#pragma unroll
    for (int i = 0; i < 6; ++i) {
        float v[4];
#pragma unroll
        for (int t = 0; t < 4; ++t) {
            const int f = i * 4 + t;                     // 0..23, compile-time
            v[t] = pos[OC * 8 + f / 3][f % 3];
        }
        slice[swz(lane * 8 + i)] = make_float4(v[0], v[1], v[2], v[3]);
    }
    asm volatile("s_waitcnt lgkmcnt(0)" ::: "memory");
    __builtin_amdgcn_sched_barrier(0);
#pragma unroll
    for (int k = 0; k < 8; ++k) {
        const int u = k * 64 + lane;                     // linear -> coalesced
        const float4 vv = slice[swz(u)];
        const int row = u >> 3, col = u & 7;
        if (col < 6)
            out4[(size_t)(wb + row) * 18 + OC * 6 + col] = vv;
    }
}

__global__ __launch_bounds__(128) void fk_kernel(
    const float* __restrict__ rot,      // [B, 24, 4]
    const float* __restrict__ skel,     // [24, 3]
    float* __restrict__ out,            // [B, 24, 3]
    int nB)
{
    __shared__ float4 lds[2 * 1024];    // 32 KiB: 2 waves x 2 slices x 8 KiB

    const int tid  = threadIdx.x;
    const int lane = tid & 63;
    const int wv   = tid >> 6;
    const int wb   = blockIdx.x * 128 + wv * 64;   // first batch of this wave

    float4* A  = &lds[wv * 1024];
    float4* Bs = A + 512;
    const float4* rot4 = reinterpret_cast<const float4*>(rot);
    float4* out4 = reinterpret_cast<float4*>(out);

    if (wb + 64 <= nB) {
        float pos[JOINTS][3];
        float4 q[8];

        // Prologue: two chunks in flight.
        issue_glds(rot4, A,  wb, lane, 0);
        issue_glds(rot4, Bs, wb, lane, 1);

        // c0: chunk0 landed (chunk1 stays in flight).
        asm volatile("s_waitcnt vmcnt(8)" ::: "memory");
        __builtin_amdgcn_sched_barrier(0);
        read_q(A, lane, q);
        issue_glds(rot4, A, wb, lane, 2);           // prefetch chunk2 over compute
        compute_chunk<0>(pos, q, skel);

        // c1: chunk1 landed (chunk2 in flight).
        asm volatile("s_waitcnt vmcnt(8)" ::: "memory");
        __builtin_amdgcn_sched_barrier(0);
        read_q(Bs, lane, q);
        compute_chunk<1>(pos, q, skel);
        store_chunk<0>(pos, Bs, out4, wb, lane);    // 8 stores queue behind chunk2

        // c2: chunk2's glds retired (vmcnt FIFO is in-order; the 8 output
        // stores issued after them may remain outstanding).
        asm volatile("s_waitcnt vmcnt(8)" ::: "memory");
        __builtin_amdgcn_sched_barrier(0);
        read_q(A, lane, q);
        compute_chunk<2>(pos, q, skel);
        store_chunk<1>(pos, A,  out4, wb, lane);
        store_chunk<2>(pos, Bs, out4, wb, lane);
    } else {
        // Partial-wave fallback (unused at B=524288): direct per-lane path.
        const int b = wb + lane;
        if (b >= nB) return;
        const float4* q4 = rot4 + (size_t)b * 24;
        float pos[JOINTS][3];
        pos[0][0] = 0.f; pos[0][1] = 0.f; pos[0][2] = 0.f;
#pragma unroll
        for (int j = 1; j < JOINTS; ++j) {
            const int p = kParents[j];
            const float ox = skel[j * 3 + 0] - skel[p * 3 + 0];
            const float oy = skel[j * 3 + 1] - skel[p * 3 + 1];
            const float oz = skel[j * 3 + 2] - skel[p * 3 + 2];
            const float4 qj = q4[j];
            const float w = qj.x, x = qj.y, y = qj.z, z = qj.w;
            const float r00 = 1.f - 2.f * (y * y + z * z);
            const float r01 = 2.f * (x * y - z * w);
            const float r02 = 2.f * (x * z + y * w);
            const float r10 = 2.f * (x * y + z * w);
            const float r11 = 1.f - 2.f * (x * x + z * z);
            const float r12 = 2.f * (y * z - x * w);
            const float r20 = 2.f * (x * z - y * w);
            const float r21 = 2.f * (y * z + x * w);
            const float r22 = 1.f - 2.f * (x * x + y * y);
            pos[j][0] = pos[p][0] + r00 * ox + r01 * oy + r02 * oz;
            pos[j][1] = pos[p][1] + r10 * ox + r11 * oy + r12 * oz;
            pos[j][2] = pos[p][2] + r20 * ox + r21 * oy + r22 * oz;
        }
        float* o = out + (size_t)b * 72;
#pragma unroll
        for (int j = 0; j < JOINTS; ++j) {
            o[j * 3 + 0] = pos[j][0];
            o[j * 3 + 1] = pos[j][1];
            o[j * 3 + 2] = pos[j][2];
        }
    }
}

extern "C" void kernel_launch(void* const* d_in, const int* in_sizes, int n_in,
                              void* d_out, int out_size, void* d_ws, size_t ws_size,
                              hipStream_t stream) {
    const float* rot  = (const float*)d_in[0];   // [B, 24, 4] f32
    const float* skel = (const float*)d_in[1];   // [24, 3] f32
    float* out = (float*)d_out;                  // [B, 24, 3] f32

    const int B = in_sizes[0] / (JOINTS * 4);    // 524288
    const int grid = (B + 127) / 128;            // 4096
    fk_kernel<<<grid, 128, 0, stream>>>(rot, skel, out, B);
}